// Round 15
// baseline (152.080 us; speedup 1.0000x reference)
//
#include <hip/hip_runtime.h>
#include <cstddef>
#include <cstdint>

#define NTOK 4096
#define NB_  8

// 0.25 (=1/sqrt(Cq)) * log2(e): folded into q so flash can use raw exp2.
#define QSCALE 0.36067376022224085f

typedef float f32x4  __attribute__((ext_vector_type(4)));
typedef float f32x16 __attribute__((ext_vector_type(16)));
typedef short s16x8  __attribute__((ext_vector_type(8)));

#if __has_builtin(__builtin_amdgcn_exp2f)
#define EXP2F(x) __builtin_amdgcn_exp2f(x)
#else
#define EXP2F(x) exp2f(x)
#endif

static __device__ __forceinline__ unsigned short f2bf(float f) {
    unsigned u = __float_as_uint(f);
    unsigned r = (u + 0x7FFFu + ((u >> 16) & 1u)) >> 16;
    return (unsigned short)r;
}

// 2 f32 -> packed bf16 pair (low half = a), RNE.
static __device__ __forceinline__ unsigned cvtpkbf(float a, float b) {
    unsigned r;
    asm("v_cvt_pk_bf16_f32 %0, %1, %2" : "=v"(r) : "v"(a), "v"(b));
    return r;
}

// v_permlane32_swap_b32: ret.x = [a(lanes0-31) | b(lanes0-31)],
//                        ret.y = [a(lanes32-63) | b(lanes32-63)].
static __device__ __forceinline__ uint2 plswap32(unsigned a, unsigned b) {
#if __has_builtin(__builtin_amdgcn_permlane32_swap)
    auto r = __builtin_amdgcn_permlane32_swap((int)a, (int)b, false, false);
    return make_uint2((unsigned)r[0], (unsigned)r[1]);
#else
    const int xa = (((int)threadIdx.x & 63) ^ 32) << 2;
    const unsigned pa = (unsigned)__builtin_amdgcn_ds_bpermute(xa, (int)a);
    const unsigned pb = (unsigned)__builtin_amdgcn_ds_bpermute(xa, (int)b);
    const bool hi = (threadIdx.x & 32) != 0;
    return make_uint2(hi ? pb : a, hi ? b : pa);
#endif
}

// lane^16 exchange (within each 32-lane half): ds_swizzle BitMode xor=16
static __device__ __forceinline__ unsigned swz16(unsigned v) {
    return (unsigned)__builtin_amdgcn_ds_swizzle((int)v, 0x401F);
}

// ---------------- P0: weights fp32 -> bf16 ----------------
__global__ __launch_bounds__(256) void wcvt_kernel(
    const float* __restrict__ Wq, const float* __restrict__ Wk, const float* __restrict__ Wv,
    unsigned short* __restrict__ wvb, unsigned short* __restrict__ wqb,
    unsigned short* __restrict__ wkb)
{
    int i = blockIdx.x * 256 + threadIdx.x;  // 0..20479
    if (i < 16384)      wvb[i]         = f2bf(Wv[i]);
    else if (i < 18432) wqb[i - 16384] = f2bf(Wq[i - 16384]);
    else                wkb[i - 18432] = f2bf(Wk[i - 18432]);
}

// ---------------- P1: fused transpose + projections (r8 config, best measured) ----
// Flat grid 512 blocks; b = blk & 7 pins each batch to one XCD. V written in
// flash's fragment-major layout: v3[b][jt=j>>6][s=(j>>4)&3][h=(j>>3)&1][c][e=j&7].
// Dense 16B V-stores via lane^16 ds_swizzle pairing (r7-verified).
__global__ __launch_bounds__(256) void proj_kernel(
    const float* __restrict__ x,
    const unsigned short* __restrict__ wvb, const unsigned short* __restrict__ wqb,
    const unsigned short* __restrict__ wkb,
    const float* __restrict__ bq, const float* __restrict__ bk, const float* __restrict__ bv,
    unsigned short* __restrict__ qb, unsigned short* __restrict__ kb,
    unsigned short* __restrict__ vt)
{
    __shared__ float lt[128][68];   // [c][n0..63], padded rows (16B-aligned stride)
    const int t = threadIdx.x;
    const int w = t >> 6, lane = t & 63;
    const int c16 = lane & 15, g16 = lane >> 4;
    const int b  = blockIdx.x & 7;
    const int n0 = (blockIdx.x >> 3) * 64;

    // stage x tile: 128 rows x 64 floats
    {
        const int n4 = t & 15;
#pragma unroll
        for (int pass = 0; pass < 8; ++pass) {
            const int c = (t >> 4) + 16 * pass;
            const float4 val = ((const float4*)(x + ((size_t)b * 128 + c) * NTOK + n0))[n4];
            *(float4*)&lt[c][n4 * 4] = val;
        }
    }
    __syncthreads();

    // xf fragments for this wave's 16 tokens (token = n0 + 16w + c16)
    const int nl = 16 * w + c16;
    s16x8 xf[4];
#pragma unroll
    for (int kc = 0; kc < 4; ++kc) {
        unsigned rr[8];
#pragma unroll
        for (int i = 0; i < 8; ++i) {
            const unsigned u = __float_as_uint(lt[32 * kc + 8 * g16 + i][nl]);
            rr[i] = u + 0x7FFFu + ((u >> 16) & 1u);
        }
        union { s16x8 v; unsigned u[4]; } cvt;
#pragma unroll
        for (int d = 0; d < 4; ++d)
            cvt.u[d] = __builtin_amdgcn_perm(rr[2 * d + 1], rr[2 * d], 0x07060302u);
        xf[kc] = cvt.v;
    }

    // ---- V = Wv * X  (fragment-major, dense 16B stores) ----
    unsigned short* vwp16 = vt + (size_t)b * (NTOK * 128) +
                            (size_t)(((n0 >> 6) * 8) + 2 * w + (g16 >> 1)) * 1024;
    const bool oddg = (g16 & 1) != 0;
#pragma unroll
    for (int mp = 0; mp < 4; ++mp) {
        f32x4 accA = {0.f, 0.f, 0.f, 0.f}, accB = {0.f, 0.f, 0.f, 0.f};
#pragma unroll
        for (int kc = 0; kc < 4; ++kc) {
            const s16x8 wfA = *(const s16x8*)(wvb + (size_t)(32 * mp      + c16) * 128 + 32 * kc + 8 * g16);
            const s16x8 wfB = *(const s16x8*)(wvb + (size_t)(32 * mp + 16 + c16) * 128 + 32 * kc + 8 * g16);
            accA = __builtin_amdgcn_mfma_f32_16x16x32_bf16(xf[kc], wfA, accA, 0, 0, 0);
            accB = __builtin_amdgcn_mfma_f32_16x16x32_bf16(xf[kc], wfB, accB, 0, 0, 0);
        }
        const float bvA = bv[32 * mp + c16], bvB = bv[32 * mp + 16 + c16];
        uint2 A, B;
        A.x = cvtpkbf(accA[0] + bvA, accA[1] + bvA);
        A.y = cvtpkbf(accA[2] + bvA, accA[3] + bvA);
        B.x = cvtpkbf(accB[0] + bvB, accB[1] + bvB);
        B.y = cvtpkbf(accB[2] + bvB, accB[3] + bvB);
        // exchange with lane^16: even lane keeps channel A row, odd keeps B row.
        const unsigned s0 = swz16(oddg ? A.x : B.x);
        const unsigned s1 = swz16(oddg ? A.y : B.y);
        uint4 W;
        W.x = oddg ? s0 : A.x;
        W.y = oddg ? s1 : A.y;
        W.z = oddg ? B.x : s0;
        W.w = oddg ? B.y : s1;
        const int crow = 32 * mp + (oddg ? 16 : 0) + c16;
        *(uint4*)(vwp16 + (size_t)crow * 8) = W;
    }
    // ---- Q, K ----
    f32x4 aq = {0.f, 0.f, 0.f, 0.f}, ak = {0.f, 0.f, 0.f, 0.f};
#pragma unroll
    for (int kc = 0; kc < 4; ++kc) {
        const s16x8 wqf = *(const s16x8*)(wqb + (size_t)c16 * 128 + 32 * kc + 8 * g16);
        const s16x8 wkf = *(const s16x8*)(wkb + (size_t)c16 * 128 + 32 * kc + 8 * g16);
        aq = __builtin_amdgcn_mfma_f32_16x16x32_bf16(wqf, xf[kc], aq, 0, 0, 0);
        ak = __builtin_amdgcn_mfma_f32_16x16x32_bf16(wkf, xf[kc], ak, 0, 0, 0);
    }
    const float4 bq4 = *(const float4*)(bq + 4 * g16);
    const float4 bk4 = *(const float4*)(bk + 4 * g16);
    const int n = n0 + 16 * w + c16;
    uint2 pq, pkk;
    pq.x  = cvtpkbf(QSCALE * (aq[0] + bq4.x), QSCALE * (aq[1] + bq4.y));
    pq.y  = cvtpkbf(QSCALE * (aq[2] + bq4.z), QSCALE * (aq[3] + bq4.w));
    pkk.x = cvtpkbf(ak[0] + bk4.x, ak[1] + bk4.y);
    pkk.y = cvtpkbf(ak[2] + bk4.z, ak[3] + bk4.w);
    *(uint2*)(qb + ((size_t)b * NTOK + n) * 16 + 4 * g16) = pq;
    *(uint2*)(kb + ((size_t)b * NTOK + n) * 16 + 4 * g16) = pkk;
}

// ---------------- P2: flash attention, Q-blocked x4 (128 rows/wave) ----------
// Grid 256 blocks (1/CU): b = blk & 7 (XCD-pinned batch), m-tile = blk>>3
// (128 q rows). 4 waves = (jw 0..1) x (cv 0..1): wave owns ALL 128 rows (four
// row-tiles rt), j-half jw, channel pair ct in {2cv,2cv+1}. No LDS/barriers
// in the loop.
//
// r14 lesson: flash time == sum of pipe integrals (little cross-pipe overlap);
// only tiling changes the integrals. r14's Q-block x2 halved the V->L1 term
// and the measured gain matched the prediction exactly (-6.5us). This applies
// the same lever again: each V fragment now feeds FOUR PV pairs -> per-CU V
// traffic 2MB -> 1MB (L1 term 13.3 -> 6.7us). O grows to 128 regs + dual
// prefetch sets (~210 total) -> launch_bounds(256,1) (cap 512, spill
// impossible - r5 lesson). Softmax per-rt runs immediately before its 4 PV
// MFMAs so pf transients stay at 2 fragments.
// Verification: VGPR ~190-220; WRITE_SIZE stays 16384 KB (spill tripwire).
__global__ __launch_bounds__(256, 1) void flash_kernel(
    const unsigned short* __restrict__ qb, const unsigned short* __restrict__ kb,
    const unsigned short* __restrict__ vt, const float* __restrict__ x,
    const float* __restrict__ gamma, float* __restrict__ out)
{
    // cmb float[64][128] @0 (32768B); lb float[4][128] @32768 (2048B)
    __shared__ __align__(16) unsigned char smem[34816];

    const int t = threadIdx.x;
    const int w = t >> 6, lane = t & 63;
    const int m31 = lane & 31, h = lane >> 5;
    const int cv = w & 1, jw = w >> 1;
    const int b  = blockIdx.x & 7;
    const int m0 = (blockIdx.x >> 3) * 128;

    // per-wave global bases (dense 1KB per wave-load)
    const unsigned short* vp = vt + (size_t)b * (NTOK * 128) +
                               (2 * jw) * 2048 + h * 1024 + (2 * cv) * 256 + m31 * 8;
    const unsigned short* kp = kb + (size_t)b * (NTOK * 16) +
                               (size_t)(32 * jw + m31) * 16 + 8 * h;

    // Q B-frags for the four row-tiles; scale (incl. log2e) pre-folded into qb.
    const s16x8 qf0 = *(const s16x8*)(qb + ((size_t)b * NTOK + m0 +  0 + m31) * 16 + 8 * h);
    const s16x8 qf1 = *(const s16x8*)(qb + ((size_t)b * NTOK + m0 + 32 + m31) * 16 + 8 * h);
    const s16x8 qf2 = *(const s16x8*)(qb + ((size_t)b * NTOK + m0 + 64 + m31) * 16 + 8 * h);
    const s16x8 qf3 = *(const s16x8*)(qb + ((size_t)b * NTOK + m0 + 96 + m31) * 16 + 8 * h);

    // hoisted zero C-operand for the QK MFMAs
    f32x16 Z;
#pragma unroll
    for (int r = 0; r < 16; ++r) Z[r] = 0.f;

    f32x16 O0a, O0b, O1a, O1b, O2a, O2b, O3a, O3b;   // O[rt][ci]: 128 acc regs
#pragma unroll
    for (int r = 0; r < 16; ++r) {
        O0a[r] = 0.f; O0b[r] = 0.f; O1a[r] = 0.f; O1b[r] = 0.f;
        O2a[r] = 0.f; O2b[r] = 0.f; O3a[r] = 0.f; O3b[r] = 0.f;
    }
    float l0a = 0.f, l0b = 0.f, l1a = 0.f, l1b = 0.f;
    float l2a = 0.f, l2b = 0.f, l3a = 0.f, l3b = 0.f;

    s16x8 kA, a00, a01, a10, a11;   // operand set A
    s16x8 kB, b00, b01, b10, b11;   // operand set B

#define LOADSET(K, V00, V01, V10, V11, jn) do {                       \
        const unsigned short* kpn_ = kp + (size_t)(jn) * 1024;        \
        const unsigned short* vpn_ = vp + (size_t)(jn) * 8192;        \
        K   = *(const s16x8*)kpn_;                                    \
        V00 = *(const s16x8*)(vpn_);                                  \
        V01 = *(const s16x8*)(vpn_ + 256);                            \
        V10 = *(const s16x8*)(vpn_ + 2048);                           \
        V11 = *(const s16x8*)(vpn_ + 2304);                           \
    } while (0)

    // one row-tile: QK -> exp2 -> pack -> pf pair -> 4 PV MFMAs (r2-verified chain)
#define RT_STEP(K, QF, LA, LAB, OA, OB, V00, V01, V10, V11) do {                    \
        f32x16 sd_ = __builtin_amdgcn_mfma_f32_32x32x16_bf16(K, QF, Z, 0, 0, 0);    \
        uint2 pk_[4];                                                               \
        _Pragma("unroll") for (int q_ = 0; q_ < 4; ++q_) {                          \
            const float e0_ = EXP2F(sd_[4 * q_ + 0]);                               \
            const float e1_ = EXP2F(sd_[4 * q_ + 1]);                               \
            const float e2_ = EXP2F(sd_[4 * q_ + 2]);                               \
            const float e3_ = EXP2F(sd_[4 * q_ + 3]);                               \
            LA += e0_ + e2_; LAB += e1_ + e3_;                                      \
            pk_[q_].x = cvtpkbf(e0_, e1_);                                          \
            pk_[q_].y = cvtpkbf(e2_, e3_);                                          \
        }                                                                           \
        s16x8 pf0_, pf1_;                                                           \
        {                                                                           \
            const uint2 rx_ = plswap32(pk_[0].x, pk_[1].x);                         \
            const uint2 ry_ = plswap32(pk_[0].y, pk_[1].y);                         \
            union { s16x8 v; unsigned u[4]; } U_;                                   \
            U_.u[0] = rx_.x; U_.u[1] = ry_.x; U_.u[2] = rx_.y; U_.u[3] = ry_.y;     \
            pf0_ = U_.v;                                                            \
        }                                                                           \
        {                                                                           \
            const uint2 rx_ = plswap32(pk_[2].x, pk_[3].x);                         \
            const uint2 ry_ = plswap32(pk_[2].y, pk_[3].y);                         \
            union { s16x8 v; unsigned u[4]; } U_;                                   \
            U_.u[0] = rx_.x; U_.u[1] = ry_.x; U_.u[2] = rx_.y; U_.u[3] = ry_.y;     \
            pf1_ = U_.v;                                                            \
        }                                                                           \
        OA = __builtin_amdgcn_mfma_f32_32x32x16_bf16(V00, pf0_, OA, 0, 0, 0);       \
        OB = __builtin_amdgcn_mfma_f32_32x32x16_bf16(V01, pf0_, OB, 0, 0, 0);       \
        OA = __builtin_amdgcn_mfma_f32_32x32x16_bf16(V10, pf1_, OA, 0, 0, 0);       \
        OB = __builtin_amdgcn_mfma_f32_32x32x16_bf16(V11, pf1_, OB, 0, 0, 0);       \
    } while (0)

#define COMPUTE(K, V00, V01, V10, V11) do {                                         \
        RT_STEP(K, qf0, l0a, l0b, O0a, O0b, V00, V01, V10, V11);                    \
        RT_STEP(K, qf1, l1a, l1b, O1a, O1b, V00, V01, V10, V11);                    \
        RT_STEP(K, qf2, l2a, l2b, O2a, O2b, V00, V01, V10, V11);                    \
        RT_STEP(K, qf3, l3a, l3b, O3a, O3b, V00, V01, V10, V11);                    \
    } while (0)

    LOADSET(kA, a00, a01, a10, a11, 0);
    LOADSET(kB, b00, b01, b10, b11, 1);

#pragma unroll 1
    for (int jt = 0; jt < 64; jt += 2) {
        COMPUTE(kA, a00, a01, a10, a11);
        LOADSET(kA, a00, a01, a10, a11, jt + 2 < 64 ? jt + 2 : 63);
        __builtin_amdgcn_sched_barrier(0);   // pin A-loads above B-compute
        COMPUTE(kB, b00, b01, b10, b11);
        LOADSET(kB, b00, b01, b10, b11, jt + 3 < 64 ? jt + 3 : 63);
        __builtin_amdgcn_sched_barrier(0);   // pin B-loads above next A-compute
    }
#undef LOADSET
#undef RT_STEP
#undef COMPUTE

    // own-half l per row-tile (h-lanes hold disjoint j subsets of the half)
    float l0 = l0a + l0b;  l0 += __shfl_xor(l0, 32);
    float l1 = l1a + l1b;  l1 += __shfl_xor(l1, 32);
    float l2 = l2a + l2b;  l2 += __shfl_xor(l2, 32);
    float l3 = l3a + l3b;  l3 += __shfl_xor(l3, 32);

    float* cmb = (float*)smem;             // [64][128] floats (32KB)
    float* lb  = (float*)(smem + 32768);   // [4][128]
    if (lane < 32) {
        lb[w * 128 +  0 + m31] = l0;
        lb[w * 128 + 32 + m31] = l1;
        lb[w * 128 + 64 + m31] = l2;
        lb[w * 128 + 96 + m31] = l3;
    }

    // ---- pass A: combine rt 0,1 across jw (partner w^2; cv softmax duplicated) ----
    if (jw == 1) {
#pragma unroll
        for (int r = 0; r < 16; ++r) {
            cmb[(0 * 16 + r) * 128 + cv * 64 + lane] = O0a[r];
            cmb[(1 * 16 + r) * 128 + cv * 64 + lane] = O0b[r];
            cmb[(2 * 16 + r) * 128 + cv * 64 + lane] = O1a[r];
            cmb[(3 * 16 + r) * 128 + cv * 64 + lane] = O1b[r];
        }
    }
    __syncthreads();
    const float lt0 = l0 + lb[(w ^ 2) * 128 +  0 + m31];
    const float lt1 = l1 + lb[(w ^ 2) * 128 + 32 + m31];
    const float lt2 = l2 + lb[(w ^ 2) * 128 + 64 + m31];
    const float lt3 = l3 + lb[(w ^ 2) * 128 + 96 + m31];
    const float g = gamma[0];
    if (jw == 0) {
        const float li0 = 1.f / lt0, li1 = 1.f / lt1;
#pragma unroll
        for (int r = 0; r < 16; ++r) {
            const int c0 = 32 * (2 * cv + 0) + (r & 3) + 8 * (r >> 2) + 4 * h;
            const int c1 = 32 * (2 * cv + 1) + (r & 3) + 8 * (r >> 2) + 4 * h;
            float v;
            v = O0a[r] + cmb[(0 * 16 + r) * 128 + cv * 64 + lane];
            out[((size_t)b * 128 + c0) * NTOK + m0 + m31] =
                fmaf(g, v * li0, x[((size_t)b * 128 + c0) * NTOK + m0 + m31]);
            v = O0b[r] + cmb[(1 * 16 + r) * 128 + cv * 64 + lane];
            out[((size_t)b * 128 + c1) * NTOK + m0 + m31] =
                fmaf(g, v * li0, x[((size_t)b * 128 + c1) * NTOK + m0 + m31]);
            v = O1a[r] + cmb[(2 * 16 + r) * 128 + cv * 64 + lane];
            out[((size_t)b * 128 + c0) * NTOK + m0 + 32 + m31] =
                fmaf(g, v * li1, x[((size_t)b * 128 + c0) * NTOK + m0 + 32 + m31]);
            v = O1b[r] + cmb[(3 * 16 + r) * 128 + cv * 64 + lane];
            out[((size_t)b * 128 + c1) * NTOK + m0 + 32 + m31] =
                fmaf(g, v * li1, x[((size_t)b * 128 + c1) * NTOK + m0 + 32 + m31]);
        }
    }
    __syncthreads();
    // ---- pass B: combine rt 2,3 ----
    if (jw == 1) {
#pragma unroll
        for (int r = 0; r < 16; ++r) {
            cmb[(0 * 16 + r) * 128 + cv * 64 + lane] = O2a[r];
            cmb[(1 * 16 + r) * 128 + cv * 64 + lane] = O2b[r];
            cmb[(2 * 16 + r) * 128 + cv * 64 + lane] = O3a[r];
            cmb[(3 * 16 + r) * 128 + cv * 64 + lane] = O3b[r];
        }
    }
    __syncthreads();
    if (jw == 0) {
        const float li2 = 1.f / lt2, li3 = 1.f / lt3;
#pragma unroll
        for (int r = 0; r < 16; ++r) {
            const int c0 = 32 * (2 * cv + 0) + (r & 3) + 8 * (r >> 2) + 4 * h;
            const int c1 = 32 * (2 * cv + 1) + (r & 3) + 8 * (r >> 2) + 4 * h;
            float v;
            v = O2a[r] + cmb[(0 * 16 + r) * 128 + cv * 64 + lane];
            out[((size_t)b * 128 + c0) * NTOK + m0 + 64 + m31] =
                fmaf(g, v * li2, x[((size_t)b * 128 + c0) * NTOK + m0 + 64 + m31]);
            v = O2b[r] + cmb[(1 * 16 + r) * 128 + cv * 64 + lane];
            out[((size_t)b * 128 + c1) * NTOK + m0 + 64 + m31] =
                fmaf(g, v * li2, x[((size_t)b * 128 + c1) * NTOK + m0 + 64 + m31]);
            v = O3a[r] + cmb[(2 * 16 + r) * 128 + cv * 64 + lane];
            out[((size_t)b * 128 + c0) * NTOK + m0 + 96 + m31] =
                fmaf(g, v * li3, x[((size_t)b * 128 + c0) * NTOK + m0 + 96 + m31]);
            v = O3b[r] + cmb[(3 * 16 + r) * 128 + cv * 64 + lane];
            out[((size_t)b * 128 + c1) * NTOK + m0 + 96 + m31] =
                fmaf(g, v * li3, x[((size_t)b * 128 + c1) * NTOK + m0 + 96 + m31]);
        }
    }
}

extern "C" void kernel_launch(void* const* d_in, const int* in_sizes, int n_in,
                              void* d_out, int out_size, void* d_ws, size_t ws_size,
                              hipStream_t stream)
{
    const float* x     = (const float*)d_in[0];
    const float* Wq    = (const float*)d_in[1];
    const float* bq    = (const float*)d_in[2];
    const float* Wk    = (const float*)d_in[3];
    const float* bk    = (const float*)d_in[4];
    const float* Wv    = (const float*)d_in[5];
    const float* bv    = (const float*)d_in[6];
    const float* gamma = (const float*)d_in[7];
    float* out = (float*)d_out;

    // workspace (bf16 elements)
    unsigned short* qb  = (unsigned short*)d_ws;                 // 8*4096*16
    unsigned short* kb  = qb  + (size_t)NB_ * NTOK * 16;
    unsigned short* vt  = kb  + (size_t)NB_ * NTOK * 16;         // 8*128*4096 (fragment-major)
    unsigned short* wvb = vt  + (size_t)NB_ * 128 * NTOK;        // 128*128
    unsigned short* wqb = wvb + 16384;                           // 16*128
    unsigned short* wkb = wqb + 2048;

    wcvt_kernel<<<80, 256, 0, stream>>>(Wq, Wk, Wv, wvb, wqb, wkb);
    proj_kernel<<<512, 256, 0, stream>>>(x, wvb, wqb, wkb, bq, bk, bv, qb, kb, vt);
    flash_kernel<<<256, 256, 0, stream>>>(qb, kb, vt, x, gamma, out);
}

// Round 16
// 146.791 us; speedup vs baseline: 1.0360x; 1.0360x over previous
//
#include <hip/hip_runtime.h>
#include <cstddef>
#include <cstdint>

#define NTOK 4096
#define NB_  8

// 0.25 (=1/sqrt(Cq)) * log2(e): folded into q so flash can use raw exp2.
#define QSCALE 0.36067376022224085f

typedef float f32x4  __attribute__((ext_vector_type(4)));
typedef float f32x16 __attribute__((ext_vector_type(16)));
typedef short s16x8  __attribute__((ext_vector_type(8)));

#if __has_builtin(__builtin_amdgcn_exp2f)
#define EXP2F(x) __builtin_amdgcn_exp2f(x)
#else
#define EXP2F(x) exp2f(x)
#endif

static __device__ __forceinline__ unsigned short f2bf(float f) {
    unsigned u = __float_as_uint(f);
    unsigned r = (u + 0x7FFFu + ((u >> 16) & 1u)) >> 16;
    return (unsigned short)r;
}

// 2 f32 -> packed bf16 pair (low half = a), RNE.
static __device__ __forceinline__ unsigned cvtpkbf(float a, float b) {
    unsigned r;
    asm("v_cvt_pk_bf16_f32 %0, %1, %2" : "=v"(r) : "v"(a), "v"(b));
    return r;
}

// v_permlane32_swap_b32: ret.x = [a(lanes0-31) | b(lanes0-31)],
//                        ret.y = [a(lanes32-63) | b(lanes32-63)].
static __device__ __forceinline__ uint2 plswap32(unsigned a, unsigned b) {
#if __has_builtin(__builtin_amdgcn_permlane32_swap)
    auto r = __builtin_amdgcn_permlane32_swap((int)a, (int)b, false, false);
    return make_uint2((unsigned)r[0], (unsigned)r[1]);
#else
    const int xa = (((int)threadIdx.x & 63) ^ 32) << 2;
    const unsigned pa = (unsigned)__builtin_amdgcn_ds_bpermute(xa, (int)a);
    const unsigned pb = (unsigned)__builtin_amdgcn_ds_bpermute(xa, (int)b);
    const bool hi = (threadIdx.x & 32) != 0;
    return make_uint2(hi ? pb : a, hi ? b : pa);
#endif
}

// lane^16 exchange (within each 32-lane half): ds_swizzle BitMode xor=16
static __device__ __forceinline__ unsigned swz16(unsigned v) {
    return (unsigned)__builtin_amdgcn_ds_swizzle((int)v, 0x401F);
}

// ---------------- P0: weights fp32 -> bf16 ----------------
__global__ __launch_bounds__(256) void wcvt_kernel(
    const float* __restrict__ Wq, const float* __restrict__ Wk, const float* __restrict__ Wv,
    unsigned short* __restrict__ wvb, unsigned short* __restrict__ wqb,
    unsigned short* __restrict__ wkb)
{
    int i = blockIdx.x * 256 + threadIdx.x;  // 0..20479
    if (i < 16384)      wvb[i]         = f2bf(Wv[i]);
    else if (i < 18432) wqb[i - 16384] = f2bf(Wq[i - 16384]);
    else                wkb[i - 18432] = f2bf(Wk[i - 18432]);
}

// ---------------- P1: fused transpose + projections (r8 config, best measured) ----
// Flat grid 512 blocks; b = blk & 7 pins each batch to one XCD. V written in
// flash's fragment-major layout: v3[b][jt=j>>6][s=(j>>4)&3][h=(j>>3)&1][c][e=j&7].
// Dense 16B V-stores via lane^16 ds_swizzle pairing (r7-verified).
__global__ __launch_bounds__(256) void proj_kernel(
    const float* __restrict__ x,
    const unsigned short* __restrict__ wvb, const unsigned short* __restrict__ wqb,
    const unsigned short* __restrict__ wkb,
    const float* __restrict__ bq, const float* __restrict__ bk, const float* __restrict__ bv,
    unsigned short* __restrict__ qb, unsigned short* __restrict__ kb,
    unsigned short* __restrict__ vt)
{
    __shared__ float lt[128][68];   // [c][n0..63], padded rows (16B-aligned stride)
    const int t = threadIdx.x;
    const int w = t >> 6, lane = t & 63;
    const int c16 = lane & 15, g16 = lane >> 4;
    const int b  = blockIdx.x & 7;
    const int n0 = (blockIdx.x >> 3) * 64;

    // stage x tile: 128 rows x 64 floats
    {
        const int n4 = t & 15;
#pragma unroll
        for (int pass = 0; pass < 8; ++pass) {
            const int c = (t >> 4) + 16 * pass;
            const float4 val = ((const float4*)(x + ((size_t)b * 128 + c) * NTOK + n0))[n4];
            *(float4*)&lt[c][n4 * 4] = val;
        }
    }
    __syncthreads();

    // xf fragments for this wave's 16 tokens (token = n0 + 16w + c16)
    const int nl = 16 * w + c16;
    s16x8 xf[4];
#pragma unroll
    for (int kc = 0; kc < 4; ++kc) {
        unsigned rr[8];
#pragma unroll
        for (int i = 0; i < 8; ++i) {
            const unsigned u = __float_as_uint(lt[32 * kc + 8 * g16 + i][nl]);
            rr[i] = u + 0x7FFFu + ((u >> 16) & 1u);
        }
        union { s16x8 v; unsigned u[4]; } cvt;
#pragma unroll
        for (int d = 0; d < 4; ++d)
            cvt.u[d] = __builtin_amdgcn_perm(rr[2 * d + 1], rr[2 * d], 0x07060302u);
        xf[kc] = cvt.v;
    }

    // ---- V = Wv * X  (fragment-major, dense 16B stores) ----
    unsigned short* vwp16 = vt + (size_t)b * (NTOK * 128) +
                            (size_t)(((n0 >> 6) * 8) + 2 * w + (g16 >> 1)) * 1024;
    const bool oddg = (g16 & 1) != 0;
#pragma unroll
    for (int mp = 0; mp < 4; ++mp) {
        f32x4 accA = {0.f, 0.f, 0.f, 0.f}, accB = {0.f, 0.f, 0.f, 0.f};
#pragma unroll
        for (int kc = 0; kc < 4; ++kc) {
            const s16x8 wfA = *(const s16x8*)(wvb + (size_t)(32 * mp      + c16) * 128 + 32 * kc + 8 * g16);
            const s16x8 wfB = *(const s16x8*)(wvb + (size_t)(32 * mp + 16 + c16) * 128 + 32 * kc + 8 * g16);
            accA = __builtin_amdgcn_mfma_f32_16x16x32_bf16(xf[kc], wfA, accA, 0, 0, 0);
            accB = __builtin_amdgcn_mfma_f32_16x16x32_bf16(xf[kc], wfB, accB, 0, 0, 0);
        }
        const float bvA = bv[32 * mp + c16], bvB = bv[32 * mp + 16 + c16];
        uint2 A, B;
        A.x = cvtpkbf(accA[0] + bvA, accA[1] + bvA);
        A.y = cvtpkbf(accA[2] + bvA, accA[3] + bvA);
        B.x = cvtpkbf(accB[0] + bvB, accB[1] + bvB);
        B.y = cvtpkbf(accB[2] + bvB, accB[3] + bvB);
        // exchange with lane^16: even lane keeps channel A row, odd keeps B row.
        const unsigned s0 = swz16(oddg ? A.x : B.x);
        const unsigned s1 = swz16(oddg ? A.y : B.y);
        uint4 W;
        W.x = oddg ? s0 : A.x;
        W.y = oddg ? s1 : A.y;
        W.z = oddg ? B.x : s0;
        W.w = oddg ? B.y : s1;
        const int crow = 32 * mp + (oddg ? 16 : 0) + c16;
        *(uint4*)(vwp16 + (size_t)crow * 8) = W;
    }
    // ---- Q, K ----
    f32x4 aq = {0.f, 0.f, 0.f, 0.f}, ak = {0.f, 0.f, 0.f, 0.f};
#pragma unroll
    for (int kc = 0; kc < 4; ++kc) {
        const s16x8 wqf = *(const s16x8*)(wqb + (size_t)c16 * 128 + 32 * kc + 8 * g16);
        const s16x8 wkf = *(const s16x8*)(wkb + (size_t)c16 * 128 + 32 * kc + 8 * g16);
        aq = __builtin_amdgcn_mfma_f32_16x16x32_bf16(wqf, xf[kc], aq, 0, 0, 0);
        ak = __builtin_amdgcn_mfma_f32_16x16x32_bf16(wkf, xf[kc], ak, 0, 0, 0);
    }
    const float4 bq4 = *(const float4*)(bq + 4 * g16);
    const float4 bk4 = *(const float4*)(bk + 4 * g16);
    const int n = n0 + 16 * w + c16;
    uint2 pq, pkk;
    pq.x  = cvtpkbf(QSCALE * (aq[0] + bq4.x), QSCALE * (aq[1] + bq4.y));
    pq.y  = cvtpkbf(QSCALE * (aq[2] + bq4.z), QSCALE * (aq[3] + bq4.w));
    pkk.x = cvtpkbf(ak[0] + bk4.x, ak[1] + bk4.y);
    pkk.y = cvtpkbf(ak[2] + bk4.z, ak[3] + bk4.w);
    *(uint2*)(qb + ((size_t)b * NTOK + n) * 16 + 4 * g16) = pq;
    *(uint2*)(kb + ((size_t)b * NTOK + n) * 16 + 4 * g16) = pkk;
}

// ---------------- P2: flash attention, (rt,jw) wave split, dedup'd softmax ----
// Grid 512 blocks (2/CU): b = blk & 7 (XCD-pinned batch), m-tile = blk>>3
// (64 q rows). 4 waves = (rt 0..1) x (jw 0..1): wave owns 32 rows (its rt),
// the jw j-half, and ALL 4 output channel tiles. No LDS/barriers in the loop.
//
// r15 lesson: Q-block x4 regressed (occupancy 8->4 waves/CU cost more than the
// L1 saving) -> r14's geometry is the V-reuse sweet spot. r14's counters:
// VALU issue ~32us of 61.3, and HALF the softmax stream was duplicated across
// cv partners. This split makes softmax unique per wave (stream halves);
// rt-partner waves re-read the same V fragments but those hit L1 (tile-
// resident). l is accumulated by ones-MFMA (Ol += mfma(ones, pf)): kills the
// 32 la-adds/tile AND the h-exchange shfl (MFMA sums the full K internally).
// Pointers are loop-carried (+= const) with 2-tile K overread into adjacent
// workspace (harmless) - no per-iteration clamp/mul.
// Verification: VGPR ~190-215; WRITE_SIZE stays 16384 KB (spill tripwire).
__global__ __launch_bounds__(256, 2) void flash_kernel(
    const unsigned short* __restrict__ qb, const unsigned short* __restrict__ kb,
    const unsigned short* __restrict__ vt, const float* __restrict__ x,
    const float* __restrict__ gamma, float* __restrict__ out)
{
    // cmb float[8][16][64] @0 (32768B); lb float[4][32] @32768
    __shared__ __align__(16) unsigned char smem[33280];

    const int t = threadIdx.x;
    const int w = t >> 6, lane = t & 63;
    const int m31 = lane & 31, h = lane >> 5;
    const int rt = w & 1, jw = w >> 1;
    const int b  = blockIdx.x & 7;
    const int m0 = (blockIdx.x >> 3) * 64;

    // loop-carried per-lane pointers (strength-reduced; no per-iter clamp/mul)
    const unsigned short* vpc = vt + (size_t)b * (NTOK * 128) +
                                (2 * jw) * 2048 + h * 1024 + m31 * 8;
    const unsigned short* kpn = kb + (size_t)b * (NTOK * 16) +
                                (size_t)(32 * jw + m31) * 16 + 8 * h;

    // Q B-frag for this wave's 32 rows; scale (incl. log2e) pre-folded into qb.
    const s16x8 qf = *(const s16x8*)(qb + ((size_t)b * NTOK + m0 + 32 * rt + m31) * 16 + 8 * h);

    // hoisted zero C-operand and all-ones bf16 A-fragment
    f32x16 Z;
#pragma unroll
    for (int r = 0; r < 16; ++r) Z[r] = 0.f;
    union { s16x8 v; unsigned u[4]; } ONE_;
    ONE_.u[0] = ONE_.u[1] = ONE_.u[2] = ONE_.u[3] = 0x3F803F80u;
    const s16x8 onef = ONE_.v;

    f32x16 O0, O1, O2, O3, Ol;   // 4 channel tiles + l accumulator (80 acc regs)
#pragma unroll
    for (int r = 0; r < 16; ++r) { O0[r] = 0.f; O1[r] = 0.f; O2[r] = 0.f; O3[r] = 0.f; Ol[r] = 0.f; }

    // K prefetch, 2 tiles deep (overreads 2 tiles past kb at the end: lands in
    // the adjacent vt workspace region - harmless, values unused)
    s16x8 kA = *(const s16x8*)kpn;
    s16x8 kB = *(const s16x8*)(kpn + 1024);
    kpn += 2048;

    // one 64-j tile: V loads issued first (latency hides under softmax), then
    // QK -> exp2 -> pack -> permlane -> pf, then ones-MFMA l + 8 PV MFMAs.
#define TILE(K) do {                                                                \
        const s16x8 v00 = *(const s16x8*)(vpc);                                     \
        const s16x8 v01 = *(const s16x8*)(vpc + 256);                               \
        const s16x8 v02 = *(const s16x8*)(vpc + 512);                               \
        const s16x8 v03 = *(const s16x8*)(vpc + 768);                               \
        const s16x8 v10 = *(const s16x8*)(vpc + 2048);                              \
        const s16x8 v11 = *(const s16x8*)(vpc + 2304);                              \
        const s16x8 v12 = *(const s16x8*)(vpc + 2560);                              \
        const s16x8 v13 = *(const s16x8*)(vpc + 2816);                              \
        vpc += 8192;                                                                \
        __builtin_amdgcn_sched_barrier(0);                                          \
        f32x16 sd_ = __builtin_amdgcn_mfma_f32_32x32x16_bf16(K, qf, Z, 0, 0, 0);    \
        uint2 pk_[4];                                                               \
        _Pragma("unroll") for (int q_ = 0; q_ < 4; ++q_) {                          \
            const float e0_ = EXP2F(sd_[4 * q_ + 0]);                               \
            const float e1_ = EXP2F(sd_[4 * q_ + 1]);                               \
            const float e2_ = EXP2F(sd_[4 * q_ + 2]);                               \
            const float e3_ = EXP2F(sd_[4 * q_ + 3]);                               \
            pk_[q_].x = cvtpkbf(e0_, e1_);                                          \
            pk_[q_].y = cvtpkbf(e2_, e3_);                                          \
        }                                                                           \
        s16x8 pf0_, pf1_;                                                           \
        {                                                                           \
            const uint2 rx_ = plswap32(pk_[0].x, pk_[1].x);                         \
            const uint2 ry_ = plswap32(pk_[0].y, pk_[1].y);                         \
            union { s16x8 v; unsigned u[4]; } U_;                                   \
            U_.u[0] = rx_.x; U_.u[1] = ry_.x; U_.u[2] = rx_.y; U_.u[3] = ry_.y;     \
            pf0_ = U_.v;                                                            \
        }                                                                           \
        {                                                                           \
            const uint2 rx_ = plswap32(pk_[2].x, pk_[3].x);                         \
            const uint2 ry_ = plswap32(pk_[2].y, pk_[3].y);                         \
            union { s16x8 v; unsigned u[4]; } U_;                                   \
            U_.u[0] = rx_.x; U_.u[1] = ry_.x; U_.u[2] = rx_.y; U_.u[3] = ry_.y;     \
            pf1_ = U_.v;                                                            \
        }                                                                           \
        Ol = __builtin_amdgcn_mfma_f32_32x32x16_bf16(onef, pf0_, Ol, 0, 0, 0);      \
        Ol = __builtin_amdgcn_mfma_f32_32x32x16_bf16(onef, pf1_, Ol, 0, 0, 0);      \
        O0 = __builtin_amdgcn_mfma_f32_32x32x16_bf16(v00, pf0_, O0, 0, 0, 0);       \
        O1 = __builtin_amdgcn_mfma_f32_32x32x16_bf16(v01, pf0_, O1, 0, 0, 0);       \
        O2 = __builtin_amdgcn_mfma_f32_32x32x16_bf16(v02, pf0_, O2, 0, 0, 0);       \
        O3 = __builtin_amdgcn_mfma_f32_32x32x16_bf16(v03, pf0_, O3, 0, 0, 0);       \
        O0 = __builtin_amdgcn_mfma_f32_32x32x16_bf16(v10, pf1_, O0, 0, 0, 0);       \
        O1 = __builtin_amdgcn_mfma_f32_32x32x16_bf16(v11, pf1_, O1, 0, 0, 0);       \
        O2 = __builtin_amdgcn_mfma_f32_32x32x16_bf16(v12, pf1_, O2, 0, 0, 0);       \
        O3 = __builtin_amdgcn_mfma_f32_32x32x16_bf16(v13, pf1_, O3, 0, 0, 0);       \
    } while (0)

#pragma unroll 1
    for (int jt = 0; jt < 64; jt += 2) {
        TILE(kA);
        kA = *(const s16x8*)kpn; kpn += 1024;   // refill for jt+2
        __builtin_amdgcn_sched_barrier(0);      // pin K-load above next TILE
        TILE(kB);
        kB = *(const s16x8*)kpn; kpn += 1024;   // refill for jt+3
        __builtin_amdgcn_sched_barrier(0);
    }
#undef TILE

    // l for this wave's 32 rows x jw-half: all 16 Ol regs (and both h halves)
    // hold the identical row-sum for column m31 - no shuffle needed.
    const float l = Ol[0];

    float* cmb = (float*)smem;             // [8][16][64]
    float* lb  = (float*)(smem + 32768);   // [4][32]
    if (lane < 32) lb[w * 32 + m31] = l;
    if (jw == 1) {
#pragma unroll
        for (int r = 0; r < 16; ++r) {
            cmb[((rt * 4 + 0) * 16 + r) * 64 + lane] = O0[r];
            cmb[((rt * 4 + 1) * 16 + r) * 64 + lane] = O1[r];
            cmb[((rt * 4 + 2) * 16 + r) * 64 + lane] = O2[r];
            cmb[((rt * 4 + 3) * 16 + r) * 64 + lane] = O3[r];
        }
    }
    __syncthreads();
    const float l_tot = l + lb[(w ^ 2) * 32 + m31];

    if (jw == 0) {
        const float linv = 1.f / l_tot;
        const float g = gamma[0];
        const size_t rowbase = m0 + 32 * rt + m31;
#pragma unroll
        for (int r = 0; r < 16; ++r) {
            const int cb = (r & 3) + 8 * (r >> 2) + 4 * h;
            float ov;
            size_t idx;
            ov = O0[r] + cmb[((rt * 4 + 0) * 16 + r) * 64 + lane];
            idx = ((size_t)b * 128 + (0 + cb)) * NTOK + rowbase;
            out[idx] = fmaf(g, ov * linv, x[idx]);
            ov = O1[r] + cmb[((rt * 4 + 1) * 16 + r) * 64 + lane];
            idx = ((size_t)b * 128 + (32 + cb)) * NTOK + rowbase;
            out[idx] = fmaf(g, ov * linv, x[idx]);
            ov = O2[r] + cmb[((rt * 4 + 2) * 16 + r) * 64 + lane];
            idx = ((size_t)b * 128 + (64 + cb)) * NTOK + rowbase;
            out[idx] = fmaf(g, ov * linv, x[idx]);
            ov = O3[r] + cmb[((rt * 4 + 3) * 16 + r) * 64 + lane];
            idx = ((size_t)b * 128 + (96 + cb)) * NTOK + rowbase;
            out[idx] = fmaf(g, ov * linv, x[idx]);
        }
    }
}

extern "C" void kernel_launch(void* const* d_in, const int* in_sizes, int n_in,
                              void* d_out, int out_size, void* d_ws, size_t ws_size,
                              hipStream_t stream)
{
    const float* x     = (const float*)d_in[0];
    const float* Wq    = (const float*)d_in[1];
    const float* bq    = (const float*)d_in[2];
    const float* Wk    = (const float*)d_in[3];
    const float* bk    = (const float*)d_in[4];
    const float* Wv    = (const float*)d_in[5];
    const float* bv    = (const float*)d_in[6];
    const float* gamma = (const float*)d_in[7];
    float* out = (float*)d_out;

    // workspace (bf16 elements)
    unsigned short* qb  = (unsigned short*)d_ws;                 // 8*4096*16
    unsigned short* kb  = qb  + (size_t)NB_ * NTOK * 16;
    unsigned short* vt  = kb  + (size_t)NB_ * NTOK * 16;         // 8*128*4096 (fragment-major)
    unsigned short* wvb = vt  + (size_t)NB_ * 128 * NTOK;        // 128*128
    unsigned short* wqb = wvb + 16384;                           // 16*128
    unsigned short* wkb = wqb + 2048;

    wcvt_kernel<<<80, 256, 0, stream>>>(Wq, Wk, Wv, wvb, wqb, wkb);
    proj_kernel<<<512, 256, 0, stream>>>(x, wvb, wqb, wkb, bq, bk, bv, qb, kb, vt);
    flash_kernel<<<512, 256, 0, stream>>>(qb, kb, vt, x, gamma, out);
}